// Round 18
// baseline (96.652 us; speedup 1.0000x reference)
//
#include <hip/hip_runtime.h>
#include <hip/hip_bf16.h>

#define KK 3
#define CIN 256
#define COUT 64
#define NSPLIT 4
#define BB 8
#define HH 64
#define WW 64
#define K2 9
#define OC 18          // 2*K*K offset channels
#define EPS 1e-5f
#define HW (HH*WW)

typedef __attribute__((ext_vector_type(8))) short bf16x8;
typedef __attribute__((ext_vector_type(4))) float f32x4;
typedef __attribute__((ext_vector_type(4))) unsigned int u32x4;

// ---- workspace layout (in floats) ----
#define WS_BSUM  512
#define WS_HBF   1024
#define HBF_FLOATS (BB*HH*WW*CIN/2)        // bf16 h, NHWC: 4,194,304 floats
#define WS_OFFS  (WS_HBF + HBF_FLOATS)
#define OFFS_SIZE (BB*72*HH*WW)            // 2,359,296
#define WS_WDT   (WS_OFFS + OFFS_SIZE)     // bf16 [s][k][o][cin]: 147,456 shorts
#define WS_WOB   (WS_WDT + NSPLIT*K2*COUT*COUT/2)
#define WOB_ELEMS (K2*80*CIN)              // bf16 [k][sc(80)][cin]: 184,320 shorts
#define NBN_BLOCKS 2048
#define NWT_BLOCKS ((WOB_ELEMS + 255) / 256)   // 720

// fp32 -> bf16 RNE (bit-math; used in cold paths)
__device__ __host__ inline unsigned short f2bf(float f) {
    unsigned int u = __builtin_bit_cast(unsigned int, f);
    unsigned int r = (u + 0x7fffu + ((u >> 16) & 1u)) >> 16;
    return (unsigned short)r;
}
__device__ inline float bf2f(unsigned short u) {
    return __builtin_bit_cast(float, (unsigned int)u << 16);
}
// hot-path pack: 2 floats -> packed bf16x2 via v_cvt_pk_bf16_f32 (compiler-emitted)
__device__ inline unsigned int pkbf(float a, float b) {
    float2 f = {a, b};
    __hip_bfloat162 r = __float22bfloat162_rn(f);
    unsigned int u;
    __builtin_memcpy(&u, &r, 4);
    return u;
}

// K0 (merged): blocks [0,2048): BN+ReLU NCHW->bf16 NHWC (per-block scale/bias);
//              blocks [2048,2768): weight transposes + bsum (first block).
__global__ __launch_bounds__(256) void prep_kernel(const float* __restrict__ x,
                                                   const float* __restrict__ g,
                                                   const float* __restrict__ be,
                                                   const float* __restrict__ mn,
                                                   const float* __restrict__ vr,
                                                   const float* __restrict__ dw,
                                                   const float* __restrict__ ow,
                                                   const float* __restrict__ db,
                                                   float* __restrict__ ws,
                                                   unsigned short* __restrict__ hbf) {
    if (blockIdx.x < NBN_BLOCKS) {
        __shared__ float tile[64 * 65];
        __shared__ float scl[64], bil[64];
        int bid = blockIdx.x;
        int cg = bid & 3;
        int y  = (bid >> 2) & 63;
        int b  = bid >> 8;
        int t = threadIdx.x;
        if (t < 64) {
            int c = cg * 64 + t;
            float inv = rsqrtf(vr[c] + EPS);
            float sc = g[c] * inv;
            scl[t] = sc;
            bil[t] = be[c] - mn[c] * sc;
        }
        __syncthreads();
        int lane = t & 63;
        int grp  = t >> 6;
        #pragma unroll
        for (int i = 0; i < 16; i++) {
            int cl = grp * 16 + i;
            int c  = cg * 64 + cl;
            float v = x[((b * CIN + c) * HH + y) * WW + lane];
            float h = fmaxf(fmaf(v, scl[cl], bil[cl]), 0.f);
            tile[cl * 65 + lane] = h;
        }
        __syncthreads();
        int cpair = t & 31;
        int pxg   = t >> 5;
        #pragma unroll
        for (int i = 0; i < 8; i++) {
            int px = pxg * 8 + i;
            *(unsigned int*)&hbf[((size_t)(b * HH + y) * WW + px) * CIN + cg * 64 + cpair * 2] =
                pkbf(tile[(cpair * 2) * 65 + px], tile[(cpair * 2 + 1) * 65 + px]);
        }
    } else {
        int tid = (blockIdx.x - NBN_BLOCKS) * 256 + threadIdx.x;
        if (blockIdx.x == NBN_BLOCKS && threadIdx.x < COUT) {
            float s = 0.f;
            for (int i = 0; i < NSPLIT; i++) s += db[i * COUT + threadIdx.x];
            ws[WS_BSUM + threadIdx.x] = s;
        }
        if (tid < NSPLIT * K2 * COUT * COUT) {
            int cin = tid & 63;
            int o = (tid >> 6) & 63;
            int k = (tid / 4096) % 9;
            int s = tid / 36864;
            ((unsigned short*)(ws + WS_WDT))[tid] = f2bf(dw[((s * COUT + o) * COUT + cin) * 9 + k]);
        }
        if (tid < WOB_ELEMS) {
            int cin = tid & 255;
            int sc = (tid >> 8) % 80;
            int k = tid / 20480;
            unsigned short v = 0;
            if (sc < 72) {
                int s = sc / 18, c = sc % 18;
                v = f2bf(ow[((s * OC + c) * CIN + cin) * 9 + k]);
            }
            ((unsigned short*)(ws + WS_WOB))[tid] = v;
        }
    }
}

// K2: offset conv via bf16 MFMA. Block = (b,y): M=64 px, N=80, K=256/tap.
// 512 threads = 8 waves: 4 M-tiles x 2 N-groups ({0,1,2} / {3,4}) -> per-wave chain halves.
__global__ __launch_bounds__(512) void offconv_kernel(const unsigned short* __restrict__ hbf,
                                                      const float* __restrict__ offb,
                                                      const unsigned short* __restrict__ woB,
                                                      float* __restrict__ offs_out) {
    __shared__ unsigned short wlds[80 * 264];
    int tid = threadIdx.x;
    int bid = blockIdx.x + 64 * blockIdx.y;
    int b = bid & 7;
    int y = bid >> 3;
    int wv  = tid >> 6;        // wave 0..7
    int wm_ = wv & 3;          // M-tile (16 px)
    int g2  = wv >> 2;         // N-group: 0 -> nt {0,1,2}, 1 -> nt {3,4}
    int ntb = g2 ? 3 : 0;
    int ntn = g2 ? 2 : 3;
    int l  = tid & 63;
    int lm = l & 15, lk = l >> 4;
    int px = wm_ * 16 + lm;

    f32x4 acc[3];
    #pragma unroll
    for (int nt = 0; nt < 3; nt++) {
        int sc = (ntb + nt) * 16 + lm;
        float ob = (nt < ntn && sc < 72) ? offb[sc] : 0.f;
        acc[nt] = (f32x4){ob, ob, ob, ob};
    }
    const unsigned short* hb = hbf + (size_t)b * HH * WW * CIN;
    const bf16x8 zero = {};

    for (int k = 0; k < 9; k++) {
        int dy = k / 3 - 1, dx = k % 3 - 1;
        int ry = y + dy;
        if ((unsigned)ry >= (unsigned)HH) continue;   // uniform across block
        __syncthreads();
        const unsigned short* src = woB + (size_t)k * 80 * 256;
        #pragma unroll
        for (int t = 0; t < 5; t++) {
            int idx = tid + t * 512;
            int sc = idx >> 5;
            int co = (idx & 31) * 8;
            *(bf16x8*)&wlds[sc * 264 + co] = *(const bf16x8*)&src[sc * 256 + co];
        }
        __syncthreads();

        int rx = px + dx;
        bool vx = (unsigned)rx < (unsigned)WW;
        const unsigned short* arow = hb + ((size_t)ry * WW + rx) * CIN + lk * 8;
        #pragma unroll
        for (int kt = 0; kt < 8; kt++) {
            bf16x8 a = vx ? *(const bf16x8*)(arow + kt * 32) : zero;
            #pragma unroll
            for (int nt = 0; nt < 3; nt++) {
                if (nt < ntn) {   // wave-uniform predicate
                    bf16x8 bb = *(const bf16x8*)&wlds[((ntb + nt) * 16 + lm) * 264 + kt * 32 + lk * 8];
                    acc[nt] = __builtin_amdgcn_mfma_f32_16x16x32_bf16(a, bb, acc[nt], 0, 0, 0);
                }
            }
        }
    }

    #pragma unroll
    for (int nt = 0; nt < 3; nt++) {
        if (nt < ntn) {
            int sc = (ntb + nt) * 16 + lm;
            if (sc < 72) {
                float4 v = {acc[nt][0], acc[nt][1], acc[nt][2], acc[nt][3]};
                *(float4*)&offs_out[((size_t)(b * 72 + sc) * HH + y) * WW + wm_ * 16 + lk * 4] = v;
            }
        }
    }
}

// K3: deformable conv — R16 champion (50.5us): R11 structure + swizzle + cvt_pk + setprio.
// 512 threads = 2 split-pair halves x 4 waves; block = (b,y) full 64-px row; 18 iters.
// vbuf/wbuf rows are 128B with byte ^= ((row&7)<<4) on write AND read -> conflict-free.
// Per-half LDS: vbuf 8192 | wbuf 8192 | tbl 2048 = 18432 B; x2 = 36864 B.
#define RGN 18432
__global__ __launch_bounds__(512, 4) void deform_kernel(const unsigned short* __restrict__ hbf,
                                                        const float* __restrict__ offp,
                                                        const unsigned short* __restrict__ wdT,
                                                        const float* __restrict__ bsum,
                                                        float* __restrict__ out) {
    __shared__ __align__(16) char lds[2][RGN];

    int tid = threadIdx.x;
    int bid = blockIdx.x + 64 * blockIdx.y;   // XCD swizzle: b = bid & 7
    int b = bid & 7;
    int y = bid >> 3;

    int h  = tid >> 8;        // split-pair half (0,1)
    int t8 = tid & 255;
    int l  = tid & 63;
    int w4 = t8 >> 6;         // wave within half (0..3) = M-tile
    int lm = l & 15;
    int lk = l >> 4;
    int pA = t8 >> 2;         // table pixel (0..63)
    int cA = t8 & 3;          // table corner
    int sub = l >> 3;         // gather: pixel-within-group-of-8
    int chq = l & 7;          // gather: 16B channel-slice index

    char* half_ = lds[h];
    char* vbufB = half_;                  // [64 px][128B], swizzled
    char* wbufB = half_ + 8192;           // [64 o][128B], swizzled
    int2* tbl2  = (int2*)(half_ + 16384); // [64 px][4] {pos, wt-bits}

    f32x4 acc[4];
    #pragma unroll
    for (int nt = 0; nt < 4; nt++) {
        float bs = h ? 0.f : bsum[nt * 16 + lm];
        acc[nt] = (f32x4){bs, bs, bs, bs};
    }

    const unsigned short* hb = hbf + (size_t)b * HH * WW * CIN;
    const float* offbase = offp + ((size_t)(b * 72 + 2 * h * 18) * HH + y) * WW + pA;

    // one-ahead offset prefetch (it=0 -> sl=0, k=0)
    float offy_c = offbase[0];
    float offx_c = offbase[HW];

    for (int it = 0; it < 2 * K2; ++it) {
        int sl = it >= K2;
        int s  = 2 * h + sl;
        int k  = it - sl * K2;

        // (0) next-iter offset prefetch
        float offy_n = 0.f, offx_n = 0.f;
        if (it + 1 < 2 * K2) {
            int sl2 = (it + 1) >= K2;
            int k2  = (it + 1) - sl2 * K2;
            const float* oa = offbase + (size_t)(sl2 * 18 + 2 * k2) * HW;
            offy_n = oa[0];
            offx_n = oa[HW];
        }

        // (0b) weight loads early (32B/thread, contiguous 8KB tile)
        const unsigned short* wsrc = wdT + (size_t)((s * 9 + k) * 64) * 64;
        bf16x8 wr0 = *(const bf16x8*)(wsrc + t8 * 16);
        bf16x8 wr1 = *(const bf16x8*)(wsrc + t8 * 16 + 8);

        // (A) per (pixel, corner): sample position + weight -> tbl
        {
            int dy = k / 3 - 1, dx = k % 3 - 1;
            float py  = (float)(y + dy) + offy_c;
            float px_ = (float)(pA + dx) + offx_c;
            float y0f = floorf(py), x0f = floorf(px_);
            float wy1 = py - y0f, wx1 = px_ - x0f;
            int yt = (int)y0f + (cA >> 1);
            int xt = (int)x0f + (cA & 1);
            float wt = ((cA >> 1) ? wy1 : 1.f - wy1) * ((cA & 1) ? wx1 : 1.f - wx1);
            bool valid = (yt >= 0) && (yt < HH) && (xt >= 0) && (xt < WW);
            wt = valid ? wt : 0.f;
            int yi = min(max(yt, 0), HH - 1);
            int xi = min(max(xt, 0), WW - 1);
            tbl2[pA * 4 + cA] = (int2){yi * WW + xi, __builtin_bit_cast(int, wt)};
        }
        __syncthreads();   // tbl ready; prev-iter MFMA LDS reads done

        // (B) cooperative gather + fp32 blend; thread owns 2 pixels x 8 channels
        {
            int pg0 = w4 * 16 + sub;
            int pg1 = pg0 + 8;
            float v0[8], v1[8];
            #pragma unroll
            for (int j = 0; j < 8; j++) { v0[j] = 0.f; v1[j] = 0.f; }
            const unsigned short* sb = hb + s * COUT + chq * 8;
            #pragma unroll
            for (int c = 0; c < 4; c++) {
                int2 t0 = tbl2[pg0 * 4 + c];
                int2 t1 = tbl2[pg1 * 4 + c];
                bf16x8 d0 = *(const bf16x8*)(sb + (size_t)t0.x * CIN);
                bf16x8 d1 = *(const bf16x8*)(sb + (size_t)t1.x * CIN);
                float w0 = __builtin_bit_cast(float, t0.y);
                float w1 = __builtin_bit_cast(float, t1.y);
                #pragma unroll
                for (int j = 0; j < 8; j++) {
                    v0[j] = fmaf(w0, bf2f((unsigned short)d0[j]), v0[j]);
                    v1[j] = fmaf(w1, bf2f((unsigned short)d1[j]), v1[j]);
                }
            }
            u32x4 q0, q1;
            #pragma unroll
            for (int j = 0; j < 4; j++) {
                q0[j] = pkbf(v0[2 * j], v0[2 * j + 1]);
                q1[j] = pkbf(v1[2 * j], v1[2 * j + 1]);
            }
            *(u32x4*)(vbufB + pg0 * 128 + ((chq * 16) ^ ((pg0 & 7) << 4))) = q0;
            *(u32x4*)(vbufB + pg1 * 128 + ((chq * 16) ^ ((pg1 & 7) << 4))) = q1;
        }
        // wbuf write, swizzled
        {
            int wo = t8 >> 2, wq = t8 & 3;
            int sw = (wo & 7) << 4;
            *(bf16x8*)(wbufB + wo * 128 + ((wq * 32) ^ sw))      = wr0;
            *(bf16x8*)(wbufB + wo * 128 + ((wq * 32 + 16) ^ sw)) = wr1;
        }
        __syncthreads();   // vbuf/wbuf ready

        // (C) MFMA: D[px][o] += V[px][cin] * W^T[o][cin]; swizzled fragment reads
        {
            int aswz = (lm & 7) << 4;
            __builtin_amdgcn_s_setprio(1);
            #pragma unroll
            for (int ks = 0; ks < 2; ks++) {
                bf16x8 a = *(const bf16x8*)(vbufB + (w4 * 16 + lm) * 128 +
                                            ((ks * 64 + lk * 16) ^ aswz));
                #pragma unroll
                for (int nt = 0; nt < 4; nt++) {
                    bf16x8 bb = *(const bf16x8*)(wbufB + (nt * 16 + lm) * 128 +
                                                 ((ks * 64 + lk * 16) ^ aswz));
                    acc[nt] = __builtin_amdgcn_mfma_f32_16x16x32_bf16(a, bb, acc[nt], 0, 0, 0);
                }
            }
            __builtin_amdgcn_s_setprio(0);
        }

        offy_c = offy_n;
        offx_c = offx_n;
    }

    // epilogue: per-half transpose into region (aliases vbuf/wbuf), then combine halves
    __syncthreads();   // all MFMA LDS reads complete before alias reuse
    float* outT = (float*)half_;   // [o][68]
    #pragma unroll
    for (int nt = 0; nt < 4; nt++) {
        *(f32x4*)(&outT[(nt * 16 + lm) * 68 + w4 * 16 + lk * 4]) = acc[nt];
    }
    __syncthreads();
    {
        const float* o0 = (const float*)lds[0];
        const float* o1 = (const float*)lds[1];
        int o = tid >> 3, xp = (tid & 7) * 8;
        float* dst = out + (((size_t)(b * COUT + o)) * HH + y) * WW + xp;
        #pragma unroll
        for (int q = 0; q < 2; q++) {
            float4 a = *(const float4*)(&o0[o * 68 + xp + q * 4]);
            float4 c = *(const float4*)(&o1[o * 68 + xp + q * 4]);
            float4 rr = {a.x + c.x, a.y + c.y, a.z + c.z, a.w + c.w};
            *(float4*)(dst + q * 4) = rr;
        }
    }
}

extern "C" void kernel_launch(void* const* d_in, const int* in_sizes, int n_in,
                              void* d_out, int out_size, void* d_ws, size_t ws_size,
                              hipStream_t stream) {
    const float* x        = (const float*)d_in[0];
    const float* bn_gamma = (const float*)d_in[1];
    const float* bn_beta  = (const float*)d_in[2];
    const float* bn_mean  = (const float*)d_in[3];
    const float* bn_var   = (const float*)d_in[4];
    const float* offset_w = (const float*)d_in[5];
    const float* offset_b = (const float*)d_in[6];
    const float* dconv_w  = (const float*)d_in[7];
    const float* dconv_b  = (const float*)d_in[8];
    float* out = (float*)d_out;
    float* ws  = (float*)d_ws;

    unsigned short* hbf = (unsigned short*)(ws + WS_HBF);

    prep_kernel<<<NBN_BLOCKS + NWT_BLOCKS, 256, 0, stream>>>(x, bn_gamma, bn_beta, bn_mean,
                                                             bn_var, dconv_w, offset_w,
                                                             dconv_b, ws, hbf);
    offconv_kernel<<<dim3(64, 8), 512, 0, stream>>>(hbf, offset_b,
                                                    (const unsigned short*)(ws + WS_WOB),
                                                    ws + WS_OFFS);
    deform_kernel<<<dim3(64, 8), 512, 0, stream>>>(hbf, ws + WS_OFFS,
                                                   (const unsigned short*)(ws + WS_WDT),
                                                   ws + WS_BSUM, out);
}

// Round 19
// 85.342 us; speedup vs baseline: 1.1325x; 1.1325x over previous
//
#include <hip/hip_runtime.h>
#include <hip/hip_bf16.h>

#define KK 3
#define CIN 256
#define COUT 64
#define NSPLIT 4
#define BB 8
#define HH 64
#define WW 64
#define K2 9
#define OC 18          // 2*K*K offset channels
#define EPS 1e-5f
#define HW (HH*WW)

typedef __attribute__((ext_vector_type(8))) short bf16x8;
typedef __attribute__((ext_vector_type(4))) float f32x4;
typedef __attribute__((ext_vector_type(4))) unsigned int u32x4;

// ---- workspace layout (in floats) ----
#define WS_BSUM  512
#define WS_HBF   1024
#define HBF_FLOATS (BB*HH*WW*CIN/2)        // bf16 h, NHWC: 4,194,304 floats
#define WS_OFFS  (WS_HBF + HBF_FLOATS)
#define OFFS_SIZE (BB*72*HH*WW)            // 2,359,296
#define WS_WDT   (WS_OFFS + OFFS_SIZE)     // bf16 [s][k][o][cin]: 147,456 shorts
#define WS_WOB   (WS_WDT + NSPLIT*K2*COUT*COUT/2)
#define WOB_ELEMS (K2*80*CIN)              // bf16 [k][sc(80)][cin]: 184,320 shorts
#define NBN_BLOCKS 2048
#define NWT_BLOCKS ((WOB_ELEMS + 255) / 256)   // 720

// fp32 -> bf16 RNE (bit-math; used in cold paths)
__device__ __host__ inline unsigned short f2bf(float f) {
    unsigned int u = __builtin_bit_cast(unsigned int, f);
    unsigned int r = (u + 0x7fffu + ((u >> 16) & 1u)) >> 16;
    return (unsigned short)r;
}
__device__ inline float bf2f(unsigned short u) {
    return __builtin_bit_cast(float, (unsigned int)u << 16);
}
// hot-path pack: 2 floats -> packed bf16x2 via v_cvt_pk_bf16_f32 (compiler-emitted)
__device__ inline unsigned int pkbf(float a, float b) {
    float2 f = {a, b};
    __hip_bfloat162 r = __float22bfloat162_rn(f);
    unsigned int u;
    __builtin_memcpy(&u, &r, 4);
    return u;
}

// K0 (merged): blocks [0,2048): BN+ReLU NCHW->bf16 NHWC (per-block scale/bias);
//              blocks [2048,2768): weight transposes + bsum (first block).
__global__ __launch_bounds__(256) void prep_kernel(const float* __restrict__ x,
                                                   const float* __restrict__ g,
                                                   const float* __restrict__ be,
                                                   const float* __restrict__ mn,
                                                   const float* __restrict__ vr,
                                                   const float* __restrict__ dw,
                                                   const float* __restrict__ ow,
                                                   const float* __restrict__ db,
                                                   float* __restrict__ ws,
                                                   unsigned short* __restrict__ hbf) {
    if (blockIdx.x < NBN_BLOCKS) {
        __shared__ float tile[64 * 65];
        __shared__ float scl[64], bil[64];
        int bid = blockIdx.x;
        int cg = bid & 3;
        int y  = (bid >> 2) & 63;
        int b  = bid >> 8;
        int t = threadIdx.x;
        if (t < 64) {
            int c = cg * 64 + t;
            float inv = rsqrtf(vr[c] + EPS);
            float sc = g[c] * inv;
            scl[t] = sc;
            bil[t] = be[c] - mn[c] * sc;
        }
        __syncthreads();
        int lane = t & 63;
        int grp  = t >> 6;
        #pragma unroll
        for (int i = 0; i < 16; i++) {
            int cl = grp * 16 + i;
            int c  = cg * 64 + cl;
            float v = x[((b * CIN + c) * HH + y) * WW + lane];
            float h = fmaxf(fmaf(v, scl[cl], bil[cl]), 0.f);
            tile[cl * 65 + lane] = h;
        }
        __syncthreads();
        int cpair = t & 31;
        int pxg   = t >> 5;
        #pragma unroll
        for (int i = 0; i < 8; i++) {
            int px = pxg * 8 + i;
            *(unsigned int*)&hbf[((size_t)(b * HH + y) * WW + px) * CIN + cg * 64 + cpair * 2] =
                pkbf(tile[(cpair * 2) * 65 + px], tile[(cpair * 2 + 1) * 65 + px]);
        }
    } else {
        int tid = (blockIdx.x - NBN_BLOCKS) * 256 + threadIdx.x;
        if (blockIdx.x == NBN_BLOCKS && threadIdx.x < COUT) {
            float s = 0.f;
            for (int i = 0; i < NSPLIT; i++) s += db[i * COUT + threadIdx.x];
            ws[WS_BSUM + threadIdx.x] = s;
        }
        if (tid < NSPLIT * K2 * COUT * COUT) {
            int cin = tid & 63;
            int o = (tid >> 6) & 63;
            int k = (tid / 4096) % 9;
            int s = tid / 36864;
            ((unsigned short*)(ws + WS_WDT))[tid] = f2bf(dw[((s * COUT + o) * COUT + cin) * 9 + k]);
        }
        if (tid < WOB_ELEMS) {
            int cin = tid & 255;
            int sc = (tid >> 8) % 80;
            int k = tid / 20480;
            unsigned short v = 0;
            if (sc < 72) {
                int s = sc / 18, c = sc % 18;
                v = f2bf(ow[((s * OC + c) * CIN + cin) * 9 + k]);
            }
            ((unsigned short*)(ws + WS_WOB))[tid] = v;
        }
    }
}

// K2: offset conv via bf16 MFMA. Block = (b,y): M=64 px, N=80, K=256/tap. 256 threads.
__global__ __launch_bounds__(256) void offconv_kernel(const unsigned short* __restrict__ hbf,
                                                      const float* __restrict__ offb,
                                                      const unsigned short* __restrict__ woB,
                                                      float* __restrict__ offs_out) {
    __shared__ unsigned short wlds[80 * 264];
    int tid = threadIdx.x;
    int bid = blockIdx.x + 64 * blockIdx.y;
    int b = bid & 7;
    int y = bid >> 3;
    int w  = tid >> 6;
    int l  = tid & 63;
    int lm = l & 15, lk = l >> 4;
    int px = w * 16 + lm;

    f32x4 acc[5];
    #pragma unroll
    for (int nt = 0; nt < 5; nt++) {
        int sc = nt * 16 + lm;
        float ob = (sc < 72) ? offb[sc] : 0.f;
        acc[nt] = (f32x4){ob, ob, ob, ob};
    }
    const unsigned short* hb = hbf + (size_t)b * HH * WW * CIN;
    const bf16x8 zero = {};

    for (int k = 0; k < 9; k++) {
        int dy = k / 3 - 1, dx = k % 3 - 1;
        int ry = y + dy;
        if ((unsigned)ry >= (unsigned)HH) continue;
        __syncthreads();
        const unsigned short* src = woB + (size_t)k * 80 * 256;
        #pragma unroll
        for (int t = 0; t < 10; t++) {
            int idx = tid + t * 256;
            int sc = idx >> 5;
            int co = (idx & 31) * 8;
            *(bf16x8*)&wlds[sc * 264 + co] = *(const bf16x8*)&src[sc * 256 + co];
        }
        __syncthreads();

        int rx = px + dx;
        bool vx = (unsigned)rx < (unsigned)WW;
        const unsigned short* arow = hb + ((size_t)ry * WW + rx) * CIN + lk * 8;
        #pragma unroll
        for (int kt = 0; kt < 8; kt++) {
            bf16x8 a = vx ? *(const bf16x8*)(arow + kt * 32) : zero;
            #pragma unroll
            for (int nt = 0; nt < 5; nt++) {
                bf16x8 bb = *(const bf16x8*)&wlds[(nt * 16 + lm) * 264 + kt * 32 + lk * 8];
                acc[nt] = __builtin_amdgcn_mfma_f32_16x16x32_bf16(a, bb, acc[nt], 0, 0, 0);
            }
        }
    }

    #pragma unroll
    for (int nt = 0; nt < 5; nt++) {
        int sc = nt * 16 + lm;
        if (sc < 72) {
            float4 v = {acc[nt][0], acc[nt][1], acc[nt][2], acc[nt][3]};
            *(float4*)&offs_out[((size_t)(b * 72 + sc) * HH + y) * WW + w * 16 + lk * 4] = v;
        }
    }
}

// K3: deformable conv — R16 champion (50.5us): R11 structure + swizzle + cvt_pk + setprio.
// 512 threads = 2 split-pair halves x 4 waves; block = (b,y) full 64-px row; 18 iters.
// vbuf/wbuf rows are 128B with byte ^= ((row&7)<<4) on write AND read -> conflict-free.
// Per-half LDS: vbuf 8192 | wbuf 8192 | tbl 2048 = 18432 B; x2 = 36864 B.
#define RGN 18432
__global__ __launch_bounds__(512, 4) void deform_kernel(const unsigned short* __restrict__ hbf,
                                                        const float* __restrict__ offp,
                                                        const unsigned short* __restrict__ wdT,
                                                        const float* __restrict__ bsum,
                                                        float* __restrict__ out) {
    __shared__ __align__(16) char lds[2][RGN];

    int tid = threadIdx.x;
    int bid = blockIdx.x + 64 * blockIdx.y;   // XCD swizzle: b = bid & 7
    int b = bid & 7;
    int y = bid >> 3;

    int h  = tid >> 8;        // split-pair half (0,1)
    int t8 = tid & 255;
    int l  = tid & 63;
    int w4 = t8 >> 6;         // wave within half (0..3) = M-tile
    int lm = l & 15;
    int lk = l >> 4;
    int pA = t8 >> 2;         // table pixel (0..63)
    int cA = t8 & 3;          // table corner
    int sub = l >> 3;         // gather: pixel-within-group-of-8
    int chq = l & 7;          // gather: 16B channel-slice index

    char* half_ = lds[h];
    char* vbufB = half_;                  // [64 px][128B], swizzled
    char* wbufB = half_ + 8192;           // [64 o][128B], swizzled
    int2* tbl2  = (int2*)(half_ + 16384); // [64 px][4] {pos, wt-bits}

    f32x4 acc[4];
    #pragma unroll
    for (int nt = 0; nt < 4; nt++) {
        float bs = h ? 0.f : bsum[nt * 16 + lm];
        acc[nt] = (f32x4){bs, bs, bs, bs};
    }

    const unsigned short* hb = hbf + (size_t)b * HH * WW * CIN;
    const float* offbase = offp + ((size_t)(b * 72 + 2 * h * 18) * HH + y) * WW + pA;

    // one-ahead offset prefetch (it=0 -> sl=0, k=0)
    float offy_c = offbase[0];
    float offx_c = offbase[HW];

    for (int it = 0; it < 2 * K2; ++it) {
        int sl = it >= K2;
        int s  = 2 * h + sl;
        int k  = it - sl * K2;

        // (0) next-iter offset prefetch
        float offy_n = 0.f, offx_n = 0.f;
        if (it + 1 < 2 * K2) {
            int sl2 = (it + 1) >= K2;
            int k2  = (it + 1) - sl2 * K2;
            const float* oa = offbase + (size_t)(sl2 * 18 + 2 * k2) * HW;
            offy_n = oa[0];
            offx_n = oa[HW];
        }

        // (0b) weight loads early (32B/thread, contiguous 8KB tile)
        const unsigned short* wsrc = wdT + (size_t)((s * 9 + k) * 64) * 64;
        bf16x8 wr0 = *(const bf16x8*)(wsrc + t8 * 16);
        bf16x8 wr1 = *(const bf16x8*)(wsrc + t8 * 16 + 8);

        // (A) per (pixel, corner): sample position + weight -> tbl
        {
            int dy = k / 3 - 1, dx = k % 3 - 1;
            float py  = (float)(y + dy) + offy_c;
            float px_ = (float)(pA + dx) + offx_c;
            float y0f = floorf(py), x0f = floorf(px_);
            float wy1 = py - y0f, wx1 = px_ - x0f;
            int yt = (int)y0f + (cA >> 1);
            int xt = (int)x0f + (cA & 1);
            float wt = ((cA >> 1) ? wy1 : 1.f - wy1) * ((cA & 1) ? wx1 : 1.f - wx1);
            bool valid = (yt >= 0) && (yt < HH) && (xt >= 0) && (xt < WW);
            wt = valid ? wt : 0.f;
            int yi = min(max(yt, 0), HH - 1);
            int xi = min(max(xt, 0), WW - 1);
            tbl2[pA * 4 + cA] = (int2){yi * WW + xi, __builtin_bit_cast(int, wt)};
        }
        __syncthreads();   // tbl ready; prev-iter MFMA LDS reads done

        // (B) cooperative gather + fp32 blend; thread owns 2 pixels x 8 channels
        {
            int pg0 = w4 * 16 + sub;
            int pg1 = pg0 + 8;
            float v0[8], v1[8];
            #pragma unroll
            for (int j = 0; j < 8; j++) { v0[j] = 0.f; v1[j] = 0.f; }
            const unsigned short* sb = hb + s * COUT + chq * 8;
            #pragma unroll
            for (int c = 0; c < 4; c++) {
                int2 t0 = tbl2[pg0 * 4 + c];
                int2 t1 = tbl2[pg1 * 4 + c];
                bf16x8 d0 = *(const bf16x8*)(sb + (size_t)t0.x * CIN);
                bf16x8 d1 = *(const bf16x8*)(sb + (size_t)t1.x * CIN);
                float w0 = __builtin_bit_cast(float, t0.y);
                float w1 = __builtin_bit_cast(float, t1.y);
                #pragma unroll
                for (int j = 0; j < 8; j++) {
                    v0[j] = fmaf(w0, bf2f((unsigned short)d0[j]), v0[j]);
                    v1[j] = fmaf(w1, bf2f((unsigned short)d1[j]), v1[j]);
                }
            }
            u32x4 q0, q1;
            #pragma unroll
            for (int j = 0; j < 4; j++) {
                q0[j] = pkbf(v0[2 * j], v0[2 * j + 1]);
                q1[j] = pkbf(v1[2 * j], v1[2 * j + 1]);
            }
            *(u32x4*)(vbufB + pg0 * 128 + ((chq * 16) ^ ((pg0 & 7) << 4))) = q0;
            *(u32x4*)(vbufB + pg1 * 128 + ((chq * 16) ^ ((pg1 & 7) << 4))) = q1;
        }
        // wbuf write, swizzled
        {
            int wo = t8 >> 2, wq = t8 & 3;
            int sw = (wo & 7) << 4;
            *(bf16x8*)(wbufB + wo * 128 + ((wq * 32) ^ sw))      = wr0;
            *(bf16x8*)(wbufB + wo * 128 + ((wq * 32 + 16) ^ sw)) = wr1;
        }
        __syncthreads();   // vbuf/wbuf ready

        // (C) MFMA: D[px][o] += V[px][cin] * W^T[o][cin]; swizzled fragment reads
        {
            int aswz = (lm & 7) << 4;
            __builtin_amdgcn_s_setprio(1);
            #pragma unroll
            for (int ks = 0; ks < 2; ks++) {
                bf16x8 a = *(const bf16x8*)(vbufB + (w4 * 16 + lm) * 128 +
                                            ((ks * 64 + lk * 16) ^ aswz));
                #pragma unroll
                for (int nt = 0; nt < 4; nt++) {
                    bf16x8 bb = *(const bf16x8*)(wbufB + (nt * 16 + lm) * 128 +
                                                 ((ks * 64 + lk * 16) ^ aswz));
                    acc[nt] = __builtin_amdgcn_mfma_f32_16x16x32_bf16(a, bb, acc[nt], 0, 0, 0);
                }
            }
            __builtin_amdgcn_s_setprio(0);
        }

        offy_c = offy_n;
        offx_c = offx_n;
    }

    // epilogue: per-half transpose into region (aliases vbuf/wbuf), then combine halves
    __syncthreads();   // all MFMA LDS reads complete before alias reuse
    float* outT = (float*)half_;   // [o][68]
    #pragma unroll
    for (int nt = 0; nt < 4; nt++) {
        *(f32x4*)(&outT[(nt * 16 + lm) * 68 + w4 * 16 + lk * 4]) = acc[nt];
    }
    __syncthreads();
    {
        const float* o0 = (const float*)lds[0];
        const float* o1 = (const float*)lds[1];
        int o = tid >> 3, xp = (tid & 7) * 8;
        float* dst = out + (((size_t)(b * COUT + o)) * HH + y) * WW + xp;
        #pragma unroll
        for (int q = 0; q < 2; q++) {
            float4 a = *(const float4*)(&o0[o * 68 + xp + q * 4]);
            float4 c = *(const float4*)(&o1[o * 68 + xp + q * 4]);
            float4 rr = {a.x + c.x, a.y + c.y, a.z + c.z, a.w + c.w};
            *(float4*)(dst + q * 4) = rr;
        }
    }
}

extern "C" void kernel_launch(void* const* d_in, const int* in_sizes, int n_in,
                              void* d_out, int out_size, void* d_ws, size_t ws_size,
                              hipStream_t stream) {
    const float* x        = (const float*)d_in[0];
    const float* bn_gamma = (const float*)d_in[1];
    const float* bn_beta  = (const float*)d_in[2];
    const float* bn_mean  = (const float*)d_in[3];
    const float* bn_var   = (const float*)d_in[4];
    const float* offset_w = (const float*)d_in[5];
    const float* offset_b = (const float*)d_in[6];
    const float* dconv_w  = (const float*)d_in[7];
    const float* dconv_b  = (const float*)d_in[8];
    float* out = (float*)d_out;
    float* ws  = (float*)d_ws;

    unsigned short* hbf = (unsigned short*)(ws + WS_HBF);

    prep_kernel<<<NBN_BLOCKS + NWT_BLOCKS, 256, 0, stream>>>(x, bn_gamma, bn_beta, bn_mean,
                                                             bn_var, dconv_w, offset_w,
                                                             dconv_b, ws, hbf);
    offconv_kernel<<<dim3(64, 8), 256, 0, stream>>>(hbf, offset_b,
                                                    (const unsigned short*)(ws + WS_WOB),
                                                    ws + WS_OFFS);
    deform_kernel<<<dim3(64, 8), 512, 0, stream>>>(hbf, ws + WS_OFFS,
                                                   (const unsigned short*)(ws + WS_WDT),
                                                   ws + WS_BSUM, out);
}